// Round 2
// baseline (679.076 us; speedup 1.0000x reference)
//
#include <hip/hip_runtime.h>

typedef _Float16 f16;
typedef _Float16 half8 __attribute__((ext_vector_type(8)));
typedef _Float16 half4 __attribute__((ext_vector_type(4)));
typedef float floatx4 __attribute__((ext_vector_type(4)));

#define MFMA16(a, b, c) __builtin_amdgcn_mfma_f32_16x16x32_f16(a, b, c, 0, 0, 0)

union H8 { half8 v; f16 e[8]; };

// async global->LDS, 16B per lane; LDS side = wave-uniform base + lane*16
__device__ __forceinline__ void gload16(const void* g, void* l) {
    __builtin_amdgcn_global_load_lds((const __attribute__((address_space(1))) void*)g,
                                     (__attribute__((address_space(3))) void*)l, 16, 0, 0);
}

// ---------------------------------------------------------------------------
// Kernel 0: convert W_in [512*512] and W_out [512*1024] fp32 -> fp16
// ---------------------------------------------------------------------------
__global__ __launch_bounds__(256) void k_cvtw(const float* __restrict__ Wi,
                                              const float* __restrict__ Wo,
                                              f16* __restrict__ W16)
{
    int i = blockIdx.x * 256 + threadIdx.x;   // float4 index, 196608 total
    float4 v;
    f16* dst;
    if (i < 65536) {
        v = reinterpret_cast<const float4*>(Wi)[i];
        dst = W16 + (size_t)i * 4;
    } else {
        int j = i - 65536;
        v = reinterpret_cast<const float4*>(Wo)[j];
        dst = W16 + 262144 + (size_t)j * 4;
    }
    half4 h = {(f16)v.x, (f16)v.y, (f16)v.z, (f16)v.w};
    *reinterpret_cast<half4*>(dst) = h;
}

// ---------------------------------------------------------------------------
// Kernel 1: q = query @ W_in^T (fp32 A staged via gl_lds, cvt on frag read).
// Writes q into comb[:,512:] and qT[b][d][token]. 128x128 tile, BK=32.
// LDS is fragment-major: block bi holds lane l's 16B frag at bi*1024 + l*16.
// ---------------------------------------------------------------------------
__global__ __launch_bounds__(256) void k_qin(const float* __restrict__ query,
                                             const f16* __restrict__ W16,
                                             f16* __restrict__ comb,
                                             f16* __restrict__ qT)
{
    __shared__ char sm[34816];
    float* At = (float*)sm;            // 16 blocks x 256 floats (16 KB)
    f16*   Bt = (f16*)(sm + 16384);    // 8 blocks x 512 halfs (8 KB)
    const int tid = threadIdx.x, lane = tid & 63, w = tid >> 6;
    const int l15 = lane & 15, quad = lane >> 4;
    const int mbase = blockIdx.y * 128, nbase = blockIdx.x * 128;
    const int wm = (w & 1) * 64, wn = (w >> 1) * 64;
    const int ia = wm >> 4, jb = wn >> 4;

    floatx4 acc[4][4];
#pragma unroll
    for (int i = 0; i < 4; ++i)
#pragma unroll
        for (int j = 0; j < 4; ++j) acc[i][j] = (floatx4)0.f;

    for (int k0 = 0; k0 < 512; k0 += 32) {
        __syncthreads();
        // A: 16 blocks (i2 = row16-group 0..7, h = lo/hi half of 8-float frag)
#pragma unroll
        for (int jr = 0; jr < 4; ++jr) {
            int bi = jr * 4 + w, i2 = bi >> 1, h = bi & 1;
            gload16(query + (size_t)(mbase + i2 * 16 + l15) * 512 + k0 + quad * 8 + h * 4,
                    At + bi * 256);
        }
        // B: 8 blocks (j2 = col16-group)
#pragma unroll
        for (int jr = 0; jr < 2; ++jr) {
            int bj = jr * 4 + w;
            gload16(W16 + (size_t)(nbase + bj * 16 + l15) * 512 + k0 + quad * 8,
                    Bt + bj * 512);
        }
        __syncthreads();
        half8 a[4], b[4];
#pragma unroll
        for (int i = 0; i < 4; ++i) {
            float4 lo = *reinterpret_cast<float4*>(At + (ia + i) * 512 + lane * 4);
            float4 hi = *reinterpret_cast<float4*>(At + (ia + i) * 512 + 256 + lane * 4);
            H8 r;
            r.e[0] = (f16)lo.x; r.e[1] = (f16)lo.y; r.e[2] = (f16)lo.z; r.e[3] = (f16)lo.w;
            r.e[4] = (f16)hi.x; r.e[5] = (f16)hi.y; r.e[6] = (f16)hi.z; r.e[7] = (f16)hi.w;
            a[i] = r.v;
        }
#pragma unroll
        for (int j = 0; j < 4; ++j)
            b[j] = *reinterpret_cast<half8*>(Bt + (jb + j) * 512 + lane * 8);
#pragma unroll
        for (int i = 0; i < 4; ++i)
#pragma unroll
            for (int j = 0; j < 4; ++j)
                acc[i][j] = MFMA16(a[i], b[j], acc[i][j]);
    }
    __syncthreads();
    f16* ct = (f16*)sm;   // 128 x 136 halfs
#pragma unroll
    for (int i = 0; i < 4; ++i)
#pragma unroll
        for (int j = 0; j < 4; ++j)
#pragma unroll
            for (int r = 0; r < 4; ++r)
                ct[(wm + i * 16 + quad * 4 + r) * 136 + wn + j * 16 + l15] = (f16)acc[i][j][r];
    __syncthreads();
    const int bb = mbase >> 11, tb = mbase & 2047;
#pragma unroll
    for (int it = 0; it < 8; ++it) {
        int c = it * 256 + tid, r = c >> 4, c8 = (c & 15) << 3;
        *reinterpret_cast<half8*>(comb + (size_t)(mbase + r) * 1024 + 512 + nbase + c8) =
            *reinterpret_cast<half8*>(ct + r * 136 + c8);
    }
#pragma unroll
    for (int it = 0; it < 8; ++it) {
        int c = it * 256 + tid, col = c & 127, rc = (c >> 7) << 3;
        H8 hv;
#pragma unroll
        for (int r8 = 0; r8 < 8; ++r8) hv.e[r8] = ct[(rc + r8) * 136 + col];
        *reinterpret_cast<half8*>(qT + ((size_t)bb * 512 + nbase + col) * 2048 + tb + rc) = hv.v;
    }
}

// ---------------------------------------------------------------------------
// Kernel 2: S = q @ q^T, causal tiles only, fp32 packed output.
// Per group of 4 batches. grid = (136 tiles, 4 batches). BK=64.
// ---------------------------------------------------------------------------
__global__ __launch_bounds__(256) void k_sgemm(const f16* __restrict__ comb,
                                               float* __restrict__ Sg, int batch0)
{
    __shared__ char sm[32768];
    f16* At = (f16*)sm;            // 16 blocks x 512 halfs
    f16* Bt = (f16*)(sm + 16384);
    const int tid = threadIdx.x, lane = tid & 63, w = tid >> 6;
    const int l15 = lane & 15, quad = lane >> 4;
    const int wm = (w & 1) * 64, wn = (w >> 1) * 64;
    const int ia = wm >> 4, jb = wn >> 4;

    int bx = blockIdx.x, mt = 0;
    while ((mt + 1) * (mt + 2) / 2 <= bx) ++mt;
    const int nt = bx - mt * (mt + 1) / 2;
    const int b = batch0 + blockIdx.y;
    const f16* qa = comb + ((size_t)b * 2048 + mt * 128) * 1024 + 512;
    const f16* qb = comb + ((size_t)b * 2048 + nt * 128) * 1024 + 512;

    floatx4 acc[4][4];
#pragma unroll
    for (int i = 0; i < 4; ++i)
#pragma unroll
        for (int j = 0; j < 4; ++j) acc[i][j] = (floatx4)0.f;

    for (int k0 = 0; k0 < 512; k0 += 64) {
        __syncthreads();
#pragma unroll
        for (int jr = 0; jr < 4; ++jr) {
            int bi = jr * 4 + w, i2 = bi >> 1, s = bi & 1;
            gload16(qa + (size_t)(i2 * 16 + l15) * 1024 + k0 + s * 32 + quad * 8, At + bi * 512);
            gload16(qb + (size_t)(i2 * 16 + l15) * 1024 + k0 + s * 32 + quad * 8, Bt + bi * 512);
        }
        __syncthreads();
#pragma unroll
        for (int s = 0; s < 2; ++s) {
            half8 a[4], bf[4];
#pragma unroll
            for (int i = 0; i < 4; ++i)
                a[i] = *reinterpret_cast<half8*>(At + ((ia + i) * 2 + s) * 512 + lane * 8);
#pragma unroll
            for (int j = 0; j < 4; ++j)
                bf[j] = *reinterpret_cast<half8*>(Bt + ((jb + j) * 2 + s) * 512 + lane * 8);
#pragma unroll
            for (int i = 0; i < 4; ++i)
#pragma unroll
                for (int j = 0; j < 4; ++j)
                    acc[i][j] = MFMA16(a[i], bf[j], acc[i][j]);
        }
    }
    float* St = Sg + ((size_t)blockIdx.y * 136 + bx) * 16384;
#pragma unroll
    for (int i = 0; i < 4; ++i)
#pragma unroll
        for (int j = 0; j < 4; ++j)
#pragma unroll
            for (int r = 0; r < 4; ++r)
                St[(wm + i * 16 + quad * 4 + r) * 128 + wn + j * 16 + l15] = acc[i][j][r];
}

// ---------------------------------------------------------------------------
// Kernel 3: row softmax S(fp32) -> P(fp16, normalized, causal mask incl diag).
// One wave per row. grid = (512, 4 batches). Row 0 -> all zeros.
// ---------------------------------------------------------------------------
__global__ __launch_bounds__(256) void k_softmax(const float* __restrict__ Sg,
                                                 f16* __restrict__ Pg)
{
    const int tid = threadIdx.x, lane = tid & 63, w = tid >> 6;
    const int row = blockIdx.x * 4 + w;
    const int gb = blockIdx.y;
    const int mt = row >> 7;
    const size_t tbase = ((size_t)gb * 136 + (size_t)(mt * (mt + 1)) / 2) * 16384;
    const int padlen = (mt + 1) * 128;
    const int r128 = (row & 127) * 128;

    float sv[32];
    float m = -1e38f;
#pragma unroll
    for (int it = 0; it < 32; ++it) {
        int c = it * 64 + lane;
        float p = -1e38f;
        if (c < row) {
            p = Sg[tbase + (size_t)(c >> 7) * 16384 + r128 + (c & 127)];
            m = fmaxf(m, p);
        }
        sv[it] = p;
    }
#pragma unroll
    for (int msk = 32; msk >= 1; msk >>= 1) m = fmaxf(m, __shfl_xor(m, msk));
    float l = 0.f;
#pragma unroll
    for (int it = 0; it < 32; ++it) {
        int c = it * 64 + lane;
        float p = 0.f;
        if (c < row) { p = __expf(sv[it] - m); l += p; }
        sv[it] = p;
    }
#pragma unroll
    for (int msk = 32; msk >= 1; msk >>= 1) l += __shfl_xor(l, msk);
    const float invl = (row > 0) ? 1.f / l : 0.f;
#pragma unroll
    for (int it = 0; it < 32; ++it) {
        int c = it * 64 + lane;
        if (c < padlen)
            Pg[tbase + (size_t)(c >> 7) * 16384 + r128 + (c & 127)] = (f16)(sv[it] * invl);
    }
}

// ---------------------------------------------------------------------------
// Kernel 4: mix = P @ q (B = qT), fp16 gl_lds GEMM, K = (mt+1)*128.
// grid = (4 n-tiles, 64 = gb*16 + mt). Writes comb[:, 0:512].
// ---------------------------------------------------------------------------
__global__ __launch_bounds__(256) void k_pv(const f16* __restrict__ Pg,
                                            const f16* __restrict__ qT,
                                            f16* __restrict__ comb, int batch0)
{
    __shared__ char sm[34816];
    f16* At = (f16*)sm;
    f16* Bt = (f16*)(sm + 16384);
    const int tid = threadIdx.x, lane = tid & 63, w = tid >> 6;
    const int l15 = lane & 15, quad = lane >> 4;
    const int wm = (w & 1) * 64, wn = (w >> 1) * 64;
    const int ia = wm >> 4, jb = wn >> 4;
    const int nb = blockIdx.x;
    const int gb = blockIdx.y >> 4, mt = blockIdx.y & 15;
    const int b = batch0 + gb;
    const f16* Pbase = Pg + ((size_t)gb * 136 + (size_t)(mt * (mt + 1)) / 2) * 16384;
    const f16* qTb = qT + ((size_t)b * 512 + nb * 128) * 2048;

    floatx4 acc[4][4];
#pragma unroll
    for (int i = 0; i < 4; ++i)
#pragma unroll
        for (int j = 0; j < 4; ++j) acc[i][j] = (floatx4)0.f;

    const int kiters = (mt + 1) * 2;
    for (int it = 0; it < kiters; ++it) {
        const int k0 = it * 64;
        const f16* Pt = Pbase + (size_t)(k0 >> 7) * 16384 + (k0 & 64);
        __syncthreads();
#pragma unroll
        for (int jr = 0; jr < 4; ++jr) {
            int bi = jr * 4 + w, i2 = bi >> 1, s = bi & 1;
            gload16(Pt + (i2 * 16 + l15) * 128 + s * 32 + quad * 8, At + bi * 512);
            gload16(qTb + (size_t)(i2 * 16 + l15) * 2048 + k0 + s * 32 + quad * 8, Bt + bi * 512);
        }
        __syncthreads();
#pragma unroll
        for (int s = 0; s < 2; ++s) {
            half8 a[4], bf[4];
#pragma unroll
            for (int i = 0; i < 4; ++i)
                a[i] = *reinterpret_cast<half8*>(At + ((ia + i) * 2 + s) * 512 + lane * 8);
#pragma unroll
            for (int j = 0; j < 4; ++j)
                bf[j] = *reinterpret_cast<half8*>(Bt + ((jb + j) * 2 + s) * 512 + lane * 8);
#pragma unroll
            for (int i = 0; i < 4; ++i)
#pragma unroll
                for (int j = 0; j < 4; ++j)
                    acc[i][j] = MFMA16(a[i], bf[j], acc[i][j]);
        }
    }
    __syncthreads();
    f16* ct = (f16*)sm;
#pragma unroll
    for (int i = 0; i < 4; ++i)
#pragma unroll
        for (int j = 0; j < 4; ++j)
#pragma unroll
            for (int r = 0; r < 4; ++r)
                ct[(wm + i * 16 + quad * 4 + r) * 136 + wn + j * 16 + l15] = (f16)acc[i][j][r];
    __syncthreads();
#pragma unroll
    for (int it = 0; it < 8; ++it) {
        int c = it * 256 + tid, r = c >> 4, c8 = (c & 15) << 3;
        *reinterpret_cast<half8*>(comb + ((size_t)b * 2048 + mt * 128 + r) * 1024 + nb * 128 + c8) =
            *reinterpret_cast<half8*>(ct + r * 136 + c8);
    }
}

// ---------------------------------------------------------------------------
// Kernel 5: out = comb @ W_out^T (fp16 gl_lds GEMM, fp32 out). K=1024.
// ---------------------------------------------------------------------------
__global__ __launch_bounds__(256) void k_out(const f16* __restrict__ comb,
                                             const f16* __restrict__ Wo16,
                                             float* __restrict__ out)
{
    __shared__ char sm[32768];
    f16* At = (f16*)sm;
    f16* Bt = (f16*)(sm + 16384);
    const int tid = threadIdx.x, lane = tid & 63, w = tid >> 6;
    const int l15 = lane & 15, quad = lane >> 4;
    const int mbase = blockIdx.y * 128, nbase = blockIdx.x * 128;
    const int wm = (w & 1) * 64, wn = (w >> 1) * 64;
    const int ia = wm >> 4, jb = wn >> 4;

    floatx4 acc[4][4];
#pragma unroll
    for (int i = 0; i < 4; ++i)
#pragma unroll
        for (int j = 0; j < 4; ++j) acc[i][j] = (floatx4)0.f;

    for (int k0 = 0; k0 < 1024; k0 += 64) {
        __syncthreads();
#pragma unroll
        for (int jr = 0; jr < 4; ++jr) {
            int bi = jr * 4 + w, i2 = bi >> 1, s = bi & 1;
            gload16(comb + (size_t)(mbase + i2 * 16 + l15) * 1024 + k0 + s * 32 + quad * 8,
                    At + bi * 512);
            gload16(Wo16 + (size_t)(nbase + i2 * 16 + l15) * 1024 + k0 + s * 32 + quad * 8,
                    Bt + bi * 512);
        }
        __syncthreads();
#pragma unroll
        for (int s = 0; s < 2; ++s) {
            half8 a[4], bf[4];
#pragma unroll
            for (int i = 0; i < 4; ++i)
                a[i] = *reinterpret_cast<half8*>(At + ((ia + i) * 2 + s) * 512 + lane * 8);
#pragma unroll
            for (int j = 0; j < 4; ++j)
                bf[j] = *reinterpret_cast<half8*>(Bt + ((jb + j) * 2 + s) * 512 + lane * 8);
#pragma unroll
            for (int i = 0; i < 4; ++i)
#pragma unroll
                for (int j = 0; j < 4; ++j)
                    acc[i][j] = MFMA16(a[i], bf[j], acc[i][j]);
        }
    }
#pragma unroll
    for (int i = 0; i < 4; ++i)
#pragma unroll
        for (int j = 0; j < 4; ++j)
#pragma unroll
            for (int r = 0; r < 4; ++r)
                out[(size_t)(mbase + wm + i * 16 + quad * 4 + r) * 512 + nbase + wn + j * 16 + l15] =
                    acc[i][j][r];
}

extern "C" void kernel_launch(void* const* d_in, const int* in_sizes, int n_in,
                              void* d_out, int out_size, void* d_ws, size_t ws_size,
                              hipStream_t stream)
{
    const float* query = (const float*)d_in[0];
    const float* W_in  = (const float*)d_in[1];
    const float* W_out = (const float*)d_in[2];
    float* out = (float*)d_out;

    // ws layout (bytes):
    //   comb fp16 [32768][1024] (mix|q)      @ 0          (67,108,864)
    //   qT   fp16 [16][512][2048]            @ 67108864   (33,554,432)
    //   W16  fp16 [W_in 262144 | W_out 524288] @ 100663296 (1,572,864)
    //   Sg   fp32 [4][136][128][128]         @ 102236160  (35,651,584)
    //   Pg   fp16 [4][136][128][128]         @ 137887744  (17,825,792)  -> total 155,713,536
    f16* comb = (f16*)d_ws;
    f16* qT   = comb + (size_t)32768 * 1024;
    f16* W16  = qT + (size_t)16 * 512 * 2048;
    float* Sg = (float*)((char*)d_ws + 102236160ull);
    f16* Pg   = (f16*)((char*)d_ws + 137887744ull);

    k_cvtw<<<768, 256, 0, stream>>>(W_in, W_out, W16);
    k_qin<<<dim3(4, 256), 256, 0, stream>>>(query, W16, comb, qT);
    for (int g = 0; g < 4; ++g) {
        k_sgemm<<<dim3(136, 4), 256, 0, stream>>>(comb, Sg, g * 4);
        k_softmax<<<dim3(512, 4), 256, 0, stream>>>(Sg, Pg);
        k_pv<<<dim3(4, 64), 256, 0, stream>>>(Pg, qT, comb, g * 4);
    }
    k_out<<<dim3(4, 256), 256, 0, stream>>>(comb, W16 + 262144, out);
}

// Round 3
// 508.552 us; speedup vs baseline: 1.3353x; 1.3353x over previous
//
#include <hip/hip_runtime.h>

typedef _Float16 f16;
typedef _Float16 half8 __attribute__((ext_vector_type(8)));
typedef _Float16 half4 __attribute__((ext_vector_type(4)));
typedef float floatx4 __attribute__((ext_vector_type(4)));

#define MFMA16(a, b, c) __builtin_amdgcn_mfma_f32_16x16x32_f16(a, b, c, 0, 0, 0)

union H8 { half8 v; f16 e[8]; };

// async global->LDS, 16B per lane; LDS side = wave-uniform base + lane*16
__device__ __forceinline__ void gload16(const void* g, void* l) {
    __builtin_amdgcn_global_load_lds((const __attribute__((address_space(1))) void*)g,
                                     (__attribute__((address_space(3))) void*)l, 16, 0, 0);
}

// ---------------------------------------------------------------------------
// Kernel 0: convert query [16.8M], W_in [262144], W_out [524288] fp32 -> fp16
// ---------------------------------------------------------------------------
__global__ __launch_bounds__(256) void k_cvt(const float* __restrict__ query,
                                             const float* __restrict__ Wi,
                                             const float* __restrict__ Wo,
                                             f16* __restrict__ q16,
                                             f16* __restrict__ W16)
{
    int i = blockIdx.x * 256 + threadIdx.x;   // float4 index, 4390912 total
    const float4* src;
    f16* dst;
    if (i < 4194304) { src = (const float4*)query + i; dst = q16 + (size_t)i * 4; }
    else if (i < 4259840) { int j = i - 4194304; src = (const float4*)Wi + j; dst = W16 + (size_t)j * 4; }
    else { int j = i - 4259840; src = (const float4*)Wo + j; dst = W16 + 262144 + (size_t)j * 4; }
    float4 v = *src;
    half4 h = {(f16)v.x, (f16)v.y, (f16)v.z, (f16)v.w};
    *reinterpret_cast<half4*>(dst) = h;
}

// ---------------------------------------------------------------------------
// Kernel 1: q = q16 @ W16^T (pure fp16 gl_lds GEMM, BK=64, 128x128 tile).
// Epilogue: comb[:,512:] (row-major, phase A) + qT[b][d][tok] (phase B via
// column-major LDS relayout so both LDS reads and global writes are contiguous).
// ---------------------------------------------------------------------------
__global__ __launch_bounds__(256) void k_qin(const f16* __restrict__ q16,
                                             const f16* __restrict__ W16,
                                             f16* __restrict__ comb,
                                             f16* __restrict__ qT)
{
    __shared__ char sm[34816];
    f16* At = (f16*)sm;            // 16 blocks x 512 halfs
    f16* Bt = (f16*)(sm + 16384);
    const int tid = threadIdx.x, lane = tid & 63, w = tid >> 6;
    const int l15 = lane & 15, quad = lane >> 4;
    const int mbase = blockIdx.y * 128, nbase = blockIdx.x * 128;
    const int wm = (w & 1) * 64, wn = (w >> 1) * 64;
    const int ia = wm >> 4, jb = wn >> 4;

    floatx4 acc[4][4];
#pragma unroll
    for (int i = 0; i < 4; ++i)
#pragma unroll
        for (int j = 0; j < 4; ++j) acc[i][j] = (floatx4)0.f;

    for (int k0 = 0; k0 < 512; k0 += 64) {
        __syncthreads();
#pragma unroll
        for (int jr = 0; jr < 4; ++jr) {
            int bi = jr * 4 + w, i2 = bi >> 1, s = bi & 1;
            gload16(q16 + (size_t)(mbase + i2 * 16 + l15) * 512 + k0 + s * 32 + quad * 8, At + bi * 512);
            gload16(W16 + (size_t)(nbase + i2 * 16 + l15) * 512 + k0 + s * 32 + quad * 8, Bt + bi * 512);
        }
        __syncthreads();
#pragma unroll
        for (int s = 0; s < 2; ++s) {
            half8 a[4], bf[4];
#pragma unroll
            for (int i = 0; i < 4; ++i)
                a[i] = *reinterpret_cast<half8*>(At + ((ia + i) * 2 + s) * 512 + lane * 8);
#pragma unroll
            for (int j = 0; j < 4; ++j)
                bf[j] = *reinterpret_cast<half8*>(Bt + ((jb + j) * 2 + s) * 512 + lane * 8);
#pragma unroll
            for (int i = 0; i < 4; ++i)
#pragma unroll
                for (int j = 0; j < 4; ++j)
                    acc[i][j] = MFMA16(a[i], bf[j], acc[i][j]);
        }
    }
    const int bb = mbase >> 11, tb = mbase & 2047;
    f16* ct = (f16*)sm;   // phase A: row-major [128][136]
    __syncthreads();
#pragma unroll
    for (int i = 0; i < 4; ++i)
#pragma unroll
        for (int j = 0; j < 4; ++j)
#pragma unroll
            for (int r = 0; r < 4; ++r)
                ct[(wm + i * 16 + quad * 4 + r) * 136 + wn + j * 16 + l15] = (f16)acc[i][j][r];
    __syncthreads();
#pragma unroll
    for (int it = 0; it < 8; ++it) {
        int c = it * 256 + tid, r = c >> 4, c8 = (c & 15) << 3;
        *reinterpret_cast<half8*>(comb + (size_t)(mbase + r) * 1024 + 512 + nbase + c8) =
            *reinterpret_cast<half8*>(ct + r * 136 + c8);
    }
    __syncthreads();
    // phase B: column-major [128 cols][136] — vectorized half4 dumps from acc
#pragma unroll
    for (int i = 0; i < 4; ++i)
#pragma unroll
        for (int j = 0; j < 4; ++j) {
            half4 h = {(f16)acc[i][j][0], (f16)acc[i][j][1], (f16)acc[i][j][2], (f16)acc[i][j][3]};
            *reinterpret_cast<half4*>(ct + (wn + j * 16 + l15) * 136 + wm + i * 16 + quad * 4) = h;
        }
    __syncthreads();
    // qT writes: 16 lanes share a d-row -> 256 B contiguous global segments
#pragma unroll
    for (int it = 0; it < 8; ++it) {
        int c = it * 256 + tid, dd = c >> 4, tc = (c & 15) << 3;
        *reinterpret_cast<half8*>(qT + ((size_t)bb * 512 + nbase + dd) * 2048 + tb + tc) =
            *reinterpret_cast<half8*>(ct + dd * 136 + tc);
    }
}

// ---------------------------------------------------------------------------
// Kernel 2: S = q @ q^T, causal tiles only, fp32 packed output.
// grid = (136 tiles, ng batches). BK=64.
// ---------------------------------------------------------------------------
__global__ __launch_bounds__(256) void k_sgemm(const f16* __restrict__ comb,
                                               float* __restrict__ Sg, int batch0)
{
    __shared__ char sm[32768];
    f16* At = (f16*)sm;
    f16* Bt = (f16*)(sm + 16384);
    const int tid = threadIdx.x, lane = tid & 63, w = tid >> 6;
    const int l15 = lane & 15, quad = lane >> 4;
    const int wm = (w & 1) * 64, wn = (w >> 1) * 64;
    const int ia = wm >> 4, jb = wn >> 4;

    int bx = blockIdx.x, mt = 0;
    while ((mt + 1) * (mt + 2) / 2 <= bx) ++mt;
    const int nt = bx - mt * (mt + 1) / 2;
    const int b = batch0 + blockIdx.y;
    const f16* qa = comb + ((size_t)b * 2048 + mt * 128) * 1024 + 512;
    const f16* qb = comb + ((size_t)b * 2048 + nt * 128) * 1024 + 512;

    floatx4 acc[4][4];
#pragma unroll
    for (int i = 0; i < 4; ++i)
#pragma unroll
        for (int j = 0; j < 4; ++j) acc[i][j] = (floatx4)0.f;

    for (int k0 = 0; k0 < 512; k0 += 64) {
        __syncthreads();
#pragma unroll
        for (int jr = 0; jr < 4; ++jr) {
            int bi = jr * 4 + w, i2 = bi >> 1, s = bi & 1;
            gload16(qa + (size_t)(i2 * 16 + l15) * 1024 + k0 + s * 32 + quad * 8, At + bi * 512);
            gload16(qb + (size_t)(i2 * 16 + l15) * 1024 + k0 + s * 32 + quad * 8, Bt + bi * 512);
        }
        __syncthreads();
#pragma unroll
        for (int s = 0; s < 2; ++s) {
            half8 a[4], bf[4];
#pragma unroll
            for (int i = 0; i < 4; ++i)
                a[i] = *reinterpret_cast<half8*>(At + ((ia + i) * 2 + s) * 512 + lane * 8);
#pragma unroll
            for (int j = 0; j < 4; ++j)
                bf[j] = *reinterpret_cast<half8*>(Bt + ((jb + j) * 2 + s) * 512 + lane * 8);
#pragma unroll
            for (int i = 0; i < 4; ++i)
#pragma unroll
                for (int j = 0; j < 4; ++j)
                    acc[i][j] = MFMA16(a[i], bf[j], acc[i][j]);
        }
    }
    float* St = Sg + ((size_t)blockIdx.y * 136 + bx) * 16384;
#pragma unroll
    for (int i = 0; i < 4; ++i)
#pragma unroll
        for (int j = 0; j < 4; ++j)
#pragma unroll
            for (int r = 0; r < 4; ++r)
                St[(wm + i * 16 + quad * 4 + r) * 128 + wn + j * 16 + l15] = acc[i][j][r];
}

// ---------------------------------------------------------------------------
// Kernel 3: row softmax S(fp32) -> P(fp16, normalized, causal incl diag).
// One wave per row. grid = (512, ng). Row 0 -> zeros.
// ---------------------------------------------------------------------------
__global__ __launch_bounds__(256) void k_softmax(const float* __restrict__ Sg,
                                                 f16* __restrict__ Pg)
{
    const int tid = threadIdx.x, lane = tid & 63, w = tid >> 6;
    const int row = blockIdx.x * 4 + w;
    const int gb = blockIdx.y;
    const int mt = row >> 7;
    const size_t tbase = ((size_t)gb * 136 + (size_t)(mt * (mt + 1)) / 2) * 16384;
    const int padlen = (mt + 1) * 128;
    const int r128 = (row & 127) * 128;

    float sv[32];
    float m = -1e38f;
#pragma unroll
    for (int it = 0; it < 32; ++it) {
        int c = it * 64 + lane;
        float p = -1e38f;
        if (c < row) {
            p = Sg[tbase + (size_t)(c >> 7) * 16384 + r128 + (c & 127)];
            m = fmaxf(m, p);
        }
        sv[it] = p;
    }
#pragma unroll
    for (int msk = 32; msk >= 1; msk >>= 1) m = fmaxf(m, __shfl_xor(m, msk));
    float l = 0.f;
#pragma unroll
    for (int it = 0; it < 32; ++it) {
        int c = it * 64 + lane;
        float p = 0.f;
        if (c < row) { p = __expf(sv[it] - m); l += p; }
        sv[it] = p;
    }
#pragma unroll
    for (int msk = 32; msk >= 1; msk >>= 1) l += __shfl_xor(l, msk);
    const float invl = (row > 0) ? 1.f / l : 0.f;
#pragma unroll
    for (int it = 0; it < 32; ++it) {
        int c = it * 64 + lane;
        if (c < padlen)
            Pg[tbase + (size_t)(c >> 7) * 16384 + r128 + (c & 127)] = (f16)(sv[it] * invl);
    }
}

// ---------------------------------------------------------------------------
// Kernel 4: mix = P @ q (B = qT), fp16 gl_lds GEMM, K = (mt+1)*128.
// grid = (4 n-tiles, 16*ng). Writes comb[:, 0:512].
// ---------------------------------------------------------------------------
__global__ __launch_bounds__(256) void k_pv(const f16* __restrict__ Pg,
                                            const f16* __restrict__ qT,
                                            f16* __restrict__ comb, int batch0)
{
    __shared__ char sm[34816];
    f16* At = (f16*)sm;
    f16* Bt = (f16*)(sm + 16384);
    const int tid = threadIdx.x, lane = tid & 63, w = tid >> 6;
    const int l15 = lane & 15, quad = lane >> 4;
    const int wm = (w & 1) * 64, wn = (w >> 1) * 64;
    const int ia = wm >> 4, jb = wn >> 4;
    const int nb = blockIdx.x;
    const int gb = blockIdx.y >> 4, mt = blockIdx.y & 15;
    const int b = batch0 + gb;
    const f16* Pbase = Pg + ((size_t)gb * 136 + (size_t)(mt * (mt + 1)) / 2) * 16384;
    const f16* qTb = qT + ((size_t)b * 512 + nb * 128) * 2048;

    floatx4 acc[4][4];
#pragma unroll
    for (int i = 0; i < 4; ++i)
#pragma unroll
        for (int j = 0; j < 4; ++j) acc[i][j] = (floatx4)0.f;

    const int kiters = (mt + 1) * 2;
    for (int it = 0; it < kiters; ++it) {
        const int k0 = it * 64;
        const f16* Pt = Pbase + (size_t)(k0 >> 7) * 16384 + (k0 & 64);
        __syncthreads();
#pragma unroll
        for (int jr = 0; jr < 4; ++jr) {
            int bi = jr * 4 + w, i2 = bi >> 1, s = bi & 1;
            gload16(Pt + (i2 * 16 + l15) * 128 + s * 32 + quad * 8, At + bi * 512);
            gload16(qTb + (size_t)(i2 * 16 + l15) * 2048 + k0 + s * 32 + quad * 8, Bt + bi * 512);
        }
        __syncthreads();
#pragma unroll
        for (int s = 0; s < 2; ++s) {
            half8 a[4], bf[4];
#pragma unroll
            for (int i = 0; i < 4; ++i)
                a[i] = *reinterpret_cast<half8*>(At + ((ia + i) * 2 + s) * 512 + lane * 8);
#pragma unroll
            for (int j = 0; j < 4; ++j)
                bf[j] = *reinterpret_cast<half8*>(Bt + ((jb + j) * 2 + s) * 512 + lane * 8);
#pragma unroll
            for (int i = 0; i < 4; ++i)
#pragma unroll
                for (int j = 0; j < 4; ++j)
                    acc[i][j] = MFMA16(a[i], bf[j], acc[i][j]);
        }
    }
    __syncthreads();
    f16* ct = (f16*)sm;
#pragma unroll
    for (int i = 0; i < 4; ++i)
#pragma unroll
        for (int j = 0; j < 4; ++j)
#pragma unroll
            for (int r = 0; r < 4; ++r)
                ct[(wm + i * 16 + quad * 4 + r) * 136 + wn + j * 16 + l15] = (f16)acc[i][j][r];
    __syncthreads();
#pragma unroll
    for (int it = 0; it < 8; ++it) {
        int c = it * 256 + tid, r = c >> 4, c8 = (c & 15) << 3;
        *reinterpret_cast<half8*>(comb + ((size_t)b * 2048 + mt * 128 + r) * 1024 + nb * 128 + c8) =
            *reinterpret_cast<half8*>(ct + r * 136 + c8);
    }
}

// ---------------------------------------------------------------------------
// Kernel 5: out = comb @ W_out^T (fp16 gl_lds GEMM, fp32 out). K=1024.
// ---------------------------------------------------------------------------
__global__ __launch_bounds__(256) void k_out(const f16* __restrict__ comb,
                                             const f16* __restrict__ Wo16,
                                             float* __restrict__ out)
{
    __shared__ char sm[32768];
    f16* At = (f16*)sm;
    f16* Bt = (f16*)(sm + 16384);
    const int tid = threadIdx.x, lane = tid & 63, w = tid >> 6;
    const int l15 = lane & 15, quad = lane >> 4;
    const int mbase = blockIdx.y * 128, nbase = blockIdx.x * 128;
    const int wm = (w & 1) * 64, wn = (w >> 1) * 64;
    const int ia = wm >> 4, jb = wn >> 4;

    floatx4 acc[4][4];
#pragma unroll
    for (int i = 0; i < 4; ++i)
#pragma unroll
        for (int j = 0; j < 4; ++j) acc[i][j] = (floatx4)0.f;

    for (int k0 = 0; k0 < 1024; k0 += 64) {
        __syncthreads();
#pragma unroll
        for (int jr = 0; jr < 4; ++jr) {
            int bi = jr * 4 + w, i2 = bi >> 1, s = bi & 1;
            gload16(comb + (size_t)(mbase + i2 * 16 + l15) * 1024 + k0 + s * 32 + quad * 8,
                    At + bi * 512);
            gload16(Wo16 + (size_t)(nbase + i2 * 16 + l15) * 1024 + k0 + s * 32 + quad * 8,
                    Bt + bi * 512);
        }
        __syncthreads();
#pragma unroll
        for (int s = 0; s < 2; ++s) {
            half8 a[4], bf[4];
#pragma unroll
            for (int i = 0; i < 4; ++i)
                a[i] = *reinterpret_cast<half8*>(At + ((ia + i) * 2 + s) * 512 + lane * 8);
#pragma unroll
            for (int j = 0; j < 4; ++j)
                bf[j] = *reinterpret_cast<half8*>(Bt + ((jb + j) * 2 + s) * 512 + lane * 8);
#pragma unroll
            for (int i = 0; i < 4; ++i)
#pragma unroll
                for (int j = 0; j < 4; ++j)
                    acc[i][j] = MFMA16(a[i], bf[j], acc[i][j]);
        }
    }
#pragma unroll
    for (int i = 0; i < 4; ++i)
#pragma unroll
        for (int j = 0; j < 4; ++j)
#pragma unroll
            for (int r = 0; r < 4; ++r)
                out[(size_t)(mbase + wm + i * 16 + quad * 4 + r) * 512 + nbase + wn + j * 16 + l15] =
                    acc[i][j][r];
}

extern "C" void kernel_launch(void* const* d_in, const int* in_sizes, int n_in,
                              void* d_out, int out_size, void* d_ws, size_t ws_size,
                              hipStream_t stream)
{
    const float* query = (const float*)d_in[0];
    const float* W_in  = (const float*)d_in[1];
    const float* W_out = (const float*)d_in[2];
    float* out = (float*)d_out;

    // ws layout (bytes):
    //   comb fp16 [32768][1024] (mix|q)        @ 0          (67,108,864)
    //   qT   fp16 [16][512][2048]              @ 67,108,864 (33,554,432)
    //   W16  fp16 [Wi 262144 | Wo 524288]      @ 100,663,296 (1,572,864)
    //   X    @ 102,236,160:
    //     q16 fp16 [16*2048*512] (33,554,432)  -- dead after k_qin
    //     Sg fp32 [ng*136*128*128] + Pg fp16 [ng*136*128*128]  (aliases q16)
    const size_t XOFF = 102236160ull;
    f16* comb = (f16*)d_ws;
    f16* qT   = comb + (size_t)32768 * 1024;
    f16* W16  = qT + (size_t)16 * 512 * 2048;
    f16* q16  = (f16*)((char*)d_ws + XOFF);
    const size_t tilebytes6 = 136ull * 16384 * 6;   // per-batch Sg(4B)+Pg(2B)
    int ng;
    if (ws_size >= XOFF + 16 * tilebytes6)      ng = 16;
    else if (ws_size >= XOFF + 8 * tilebytes6)  ng = 8;
    else                                        ng = 4;
    float* Sg = (float*)((char*)d_ws + XOFF);
    f16* Pg   = (f16*)((char*)d_ws + XOFF + (size_t)ng * 136 * 16384 * 4);

    k_cvt<<<17152, 256, 0, stream>>>(query, W_in, W_out, q16, W16);
    k_qin<<<dim3(4, 256), 256, 0, stream>>>(q16, W16, comb, qT);
    for (int g = 0; g < 16 / ng; ++g) {
        k_sgemm<<<dim3(136, ng), 256, 0, stream>>>(comb, Sg, g * ng);
        k_softmax<<<dim3(512, ng), 256, 0, stream>>>(Sg, Pg);
        k_pv<<<dim3(4, 16 * ng), 256, 0, stream>>>(Pg, qT, comb, g * ng);
    }
    k_out<<<dim3(4, 256), 256, 0, stream>>>(comb, W16 + 262144, out);
}

// Round 4
// 465.777 us; speedup vs baseline: 1.4579x; 1.0918x over previous
//
#include <hip/hip_runtime.h>

typedef _Float16 f16;
typedef _Float16 half8 __attribute__((ext_vector_type(8)));
typedef _Float16 half4 __attribute__((ext_vector_type(4)));
typedef float floatx4 __attribute__((ext_vector_type(4)));

#define MFMA16(a, b, c) __builtin_amdgcn_mfma_f32_16x16x32_f16(a, b, c, 0, 0, 0)

union H8 { half8 v; f16 e[8]; };

// async global->LDS, 16B per lane; LDS side = wave-uniform base + lane*16
__device__ __forceinline__ void gload16(const void* g, void* l) {
    __builtin_amdgcn_global_load_lds((const __attribute__((address_space(1))) void*)g,
                                     (__attribute__((address_space(3))) void*)l, 16, 0, 0);
}

// ---------------------------------------------------------------------------
// Kernel 0: convert query [16.8M], W_in [262144], W_out [524288] fp32 -> fp16
// ---------------------------------------------------------------------------
__global__ __launch_bounds__(256) void k_cvt(const float* __restrict__ query,
                                             const float* __restrict__ Wi,
                                             const float* __restrict__ Wo,
                                             f16* __restrict__ q16,
                                             f16* __restrict__ W16)
{
    int i = blockIdx.x * 256 + threadIdx.x;   // float4 index, 4390912 total
    const float4* src;
    f16* dst;
    if (i < 4194304) { src = (const float4*)query + i; dst = q16 + (size_t)i * 4; }
    else if (i < 4259840) { int j = i - 4194304; src = (const float4*)Wi + j; dst = W16 + (size_t)j * 4; }
    else { int j = i - 4259840; src = (const float4*)Wo + j; dst = W16 + 262144 + (size_t)j * 4; }
    float4 v = *src;
    half4 h = {(f16)v.x, (f16)v.y, (f16)v.z, (f16)v.w};
    *reinterpret_cast<half4*>(dst) = h;
}

// ---------------------------------------------------------------------------
// Kernel 1: q = q16 @ W16^T (fp16 gl_lds GEMM, BK=64, 128x128 tile).
// 1D grid 1024 with XCD swizzle: the 4 n-blocks sharing one A-strip get ids
// congruent mod 8 -> same XCD -> A fetched into that L2 once.
// ---------------------------------------------------------------------------
__global__ __launch_bounds__(256) void k_qin(const f16* __restrict__ q16,
                                             const f16* __restrict__ W16,
                                             f16* __restrict__ comb,
                                             f16* __restrict__ qT)
{
    __shared__ char sm[34816];
    f16* At = (f16*)sm;            // 16 blocks x 512 halfs
    f16* Bt = (f16*)(sm + 16384);
    const int tid = threadIdx.x, lane = tid & 63, w = tid >> 6;
    const int l15 = lane & 15, quad = lane >> 4;
    const int id = blockIdx.x, xcd = id & 7, u = id >> 3;
    const int mbase = (xcd * 32 + (u >> 2)) * 128;   // m-tile 0..255
    const int nbase = (u & 3) * 128;                 // n-tile 0..3
    const int wm = (w & 1) * 64, wn = (w >> 1) * 64;
    const int ia = wm >> 4, jb = wn >> 4;

    floatx4 acc[4][4];
#pragma unroll
    for (int i = 0; i < 4; ++i)
#pragma unroll
        for (int j = 0; j < 4; ++j) acc[i][j] = (floatx4)0.f;

    for (int k0 = 0; k0 < 512; k0 += 64) {
        __syncthreads();
#pragma unroll
        for (int jr = 0; jr < 4; ++jr) {
            int bi = jr * 4 + w, i2 = bi >> 1, s = bi & 1;
            gload16(q16 + (size_t)(mbase + i2 * 16 + l15) * 512 + k0 + s * 32 + quad * 8, At + bi * 512);
            gload16(W16 + (size_t)(nbase + i2 * 16 + l15) * 512 + k0 + s * 32 + quad * 8, Bt + bi * 512);
        }
        __syncthreads();
#pragma unroll
        for (int s = 0; s < 2; ++s) {
            half8 a[4], bf[4];
#pragma unroll
            for (int i = 0; i < 4; ++i)
                a[i] = *reinterpret_cast<half8*>(At + ((ia + i) * 2 + s) * 512 + lane * 8);
#pragma unroll
            for (int j = 0; j < 4; ++j)
                bf[j] = *reinterpret_cast<half8*>(Bt + ((jb + j) * 2 + s) * 512 + lane * 8);
#pragma unroll
            for (int i = 0; i < 4; ++i)
#pragma unroll
                for (int j = 0; j < 4; ++j)
                    acc[i][j] = MFMA16(a[i], bf[j], acc[i][j]);
        }
    }
    const int bb = mbase >> 11, tb = mbase & 2047;
    f16* ct = (f16*)sm;   // phase A: row-major [128][136]
    __syncthreads();
#pragma unroll
    for (int i = 0; i < 4; ++i)
#pragma unroll
        for (int j = 0; j < 4; ++j)
#pragma unroll
            for (int r = 0; r < 4; ++r)
                ct[(wm + i * 16 + quad * 4 + r) * 136 + wn + j * 16 + l15] = (f16)acc[i][j][r];
    __syncthreads();
#pragma unroll
    for (int it = 0; it < 8; ++it) {
        int c = it * 256 + tid, r = c >> 4, c8 = (c & 15) << 3;
        *reinterpret_cast<half8*>(comb + (size_t)(mbase + r) * 1024 + 512 + nbase + c8) =
            *reinterpret_cast<half8*>(ct + r * 136 + c8);
    }
    __syncthreads();
    // phase B: column-major [128 cols][136] — vectorized half4 dumps from acc
#pragma unroll
    for (int i = 0; i < 4; ++i)
#pragma unroll
        for (int j = 0; j < 4; ++j) {
            half4 h = {(f16)acc[i][j][0], (f16)acc[i][j][1], (f16)acc[i][j][2], (f16)acc[i][j][3]};
            *reinterpret_cast<half4*>(ct + (wn + j * 16 + l15) * 136 + wm + i * 16 + quad * 4) = h;
        }
    __syncthreads();
    // qT writes: 16 lanes share a d-row -> 256 B contiguous global segments
#pragma unroll
    for (int it = 0; it < 8; ++it) {
        int c = it * 256 + tid, dd = c >> 4, tc = (c & 15) << 3;
        *reinterpret_cast<half8*>(qT + ((size_t)bb * 512 + nbase + dd) * 2048 + tb + tc) =
            *reinterpret_cast<half8*>(ct + dd * 136 + tc);
    }
}

// ---------------------------------------------------------------------------
// Kernel 2: S = q @ q^T, causal tiles only, fp32 packed output.
// grid = (136 tiles, ng batches). BK=64.
// ---------------------------------------------------------------------------
__global__ __launch_bounds__(256) void k_sgemm(const f16* __restrict__ comb,
                                               float* __restrict__ Sg, int batch0)
{
    __shared__ char sm[32768];
    f16* At = (f16*)sm;
    f16* Bt = (f16*)(sm + 16384);
    const int tid = threadIdx.x, lane = tid & 63, w = tid >> 6;
    const int l15 = lane & 15, quad = lane >> 4;
    const int wm = (w & 1) * 64, wn = (w >> 1) * 64;
    const int ia = wm >> 4, jb = wn >> 4;

    int bx = blockIdx.x, mt = 0;
    while ((mt + 1) * (mt + 2) / 2 <= bx) ++mt;
    const int nt = bx - mt * (mt + 1) / 2;
    const int b = batch0 + blockIdx.y;
    const f16* qa = comb + ((size_t)b * 2048 + mt * 128) * 1024 + 512;
    const f16* qb = comb + ((size_t)b * 2048 + nt * 128) * 1024 + 512;

    floatx4 acc[4][4];
#pragma unroll
    for (int i = 0; i < 4; ++i)
#pragma unroll
        for (int j = 0; j < 4; ++j) acc[i][j] = (floatx4)0.f;

    for (int k0 = 0; k0 < 512; k0 += 64) {
        __syncthreads();
#pragma unroll
        for (int jr = 0; jr < 4; ++jr) {
            int bi = jr * 4 + w, i2 = bi >> 1, s = bi & 1;
            gload16(qa + (size_t)(i2 * 16 + l15) * 1024 + k0 + s * 32 + quad * 8, At + bi * 512);
            gload16(qb + (size_t)(i2 * 16 + l15) * 1024 + k0 + s * 32 + quad * 8, Bt + bi * 512);
        }
        __syncthreads();
#pragma unroll
        for (int s = 0; s < 2; ++s) {
            half8 a[4], bf[4];
#pragma unroll
            for (int i = 0; i < 4; ++i)
                a[i] = *reinterpret_cast<half8*>(At + ((ia + i) * 2 + s) * 512 + lane * 8);
#pragma unroll
            for (int j = 0; j < 4; ++j)
                bf[j] = *reinterpret_cast<half8*>(Bt + ((jb + j) * 2 + s) * 512 + lane * 8);
#pragma unroll
            for (int i = 0; i < 4; ++i)
#pragma unroll
                for (int j = 0; j < 4; ++j)
                    acc[i][j] = MFMA16(a[i], bf[j], acc[i][j]);
        }
    }
    float* St = Sg + ((size_t)blockIdx.y * 136 + bx) * 16384;
#pragma unroll
    for (int i = 0; i < 4; ++i)
#pragma unroll
        for (int j = 0; j < 4; ++j)
#pragma unroll
            for (int r = 0; r < 4; ++r)
                St[(wm + i * 16 + quad * 4 + r) * 128 + wn + j * 16 + l15] = acc[i][j][r];
}

// ---------------------------------------------------------------------------
// Kernel 3: row softmax, IN-PLACE: reads fp32 S row, writes normalized fp16 P
// into the first half of the same row's storage. Each row is owned by exactly
// one wave (full row registered in sv[] before any store) -> no hazard.
// Single non-restrict pointer (S and P alias).
// ---------------------------------------------------------------------------
__global__ __launch_bounds__(256) void k_softmax(float* Sg)
{
    const int tid = threadIdx.x, lane = tid & 63, w = tid >> 6;
    const int row = blockIdx.x * 4 + w;
    const int gb = blockIdx.y;
    const int mt = row >> 7;
    const size_t tbase = ((size_t)gb * 136 + (size_t)(mt * (mt + 1)) / 2) * 16384;
    const int padlen = (mt + 1) * 128;
    const int r128 = (row & 127) * 128;
    f16* Ph = (f16*)Sg;

    float sv[32];
    float m = -1e38f;
#pragma unroll
    for (int it = 0; it < 32; ++it) {
        int c = it * 64 + lane;
        float p = -1e38f;
        if (c < row) {
            p = Sg[tbase + (size_t)(c >> 7) * 16384 + r128 + (c & 127)];
            m = fmaxf(m, p);
        }
        sv[it] = p;
    }
#pragma unroll
    for (int msk = 32; msk >= 1; msk >>= 1) m = fmaxf(m, __shfl_xor(m, msk));
    float l = 0.f;
#pragma unroll
    for (int it = 0; it < 32; ++it) {
        int c = it * 64 + lane;
        float p = 0.f;
        if (c < row) { p = __expf(sv[it] - m); l += p; }
        sv[it] = p;
    }
#pragma unroll
    for (int msk = 32; msk >= 1; msk >>= 1) l += __shfl_xor(l, msk);
    const float invl = (row > 0) ? 1.f / l : 0.f;
#pragma unroll
    for (int it = 0; it < 32; ++it) {
        int c = it * 64 + lane;
        if (c < padlen)
            Ph[2 * (tbase + (size_t)(c >> 7) * 16384 + r128) + (c & 127)] = (f16)(sv[it] * invl);
    }
}

// ---------------------------------------------------------------------------
// Kernel 4: mix = P @ q (B = qT), fp16 gl_lds GEMM, K = (mt+1)*128.
// P read in-place from the Sg region (fp16 rows at stride 256 halfs).
// 1D grid 64*ng, XCD swizzle: 4 nb-blocks of one (gb,mt) strip -> same XCD;
// mt paired with 15-mt per XCD for load balance.
// ---------------------------------------------------------------------------
__global__ __launch_bounds__(256) void k_pv(const float* Sg,
                                            const f16* __restrict__ qT,
                                            f16* __restrict__ comb, int batch0)
{
    __shared__ char sm[34816];
    f16* At = (f16*)sm;
    f16* Bt = (f16*)(sm + 16384);
    const int tid = threadIdx.x, lane = tid & 63, w = tid >> 6;
    const int l15 = lane & 15, quad = lane >> 4;
    const int wm = (w & 1) * 64, wn = (w >> 1) * 64;
    const int ia = wm >> 4, jb = wn >> 4;
    const int id = blockIdx.x, xcd = id & 7, u = id >> 3;
    const int nb = u & 3, v = u >> 2;
    const int gb = v >> 1;
    const int mt = (v & 1) ? (15 - xcd) : xcd;
    const int b = batch0 + gb;
    const int tb0 = mt * (mt + 1) / 2;
    const f16* Ph = (const f16*)(Sg + (size_t)gb * 136 * 16384);
    const f16* qTb = qT + ((size_t)b * 512 + nb * 128) * 2048;

    floatx4 acc[4][4];
#pragma unroll
    for (int i = 0; i < 4; ++i)
#pragma unroll
        for (int j = 0; j < 4; ++j) acc[i][j] = (floatx4)0.f;

    const int kiters = (mt + 1) * 2;
    for (int it = 0; it < kiters; ++it) {
        const int k0 = it * 64;
        const int t = tb0 + (k0 >> 7), c0 = k0 & 64;
        __syncthreads();
#pragma unroll
        for (int jr = 0; jr < 4; ++jr) {
            int bi = jr * 4 + w, i2 = bi >> 1, s = bi & 1;
            gload16(Ph + 2 * ((size_t)t * 16384 + (size_t)(i2 * 16 + l15) * 128) + c0 + s * 32 + quad * 8,
                    At + bi * 512);
            gload16(qTb + (size_t)(i2 * 16 + l15) * 2048 + k0 + s * 32 + quad * 8, Bt + bi * 512);
        }
        __syncthreads();
#pragma unroll
        for (int s = 0; s < 2; ++s) {
            half8 a[4], bf[4];
#pragma unroll
            for (int i = 0; i < 4; ++i)
                a[i] = *reinterpret_cast<half8*>(At + ((ia + i) * 2 + s) * 512 + lane * 8);
#pragma unroll
            for (int j = 0; j < 4; ++j)
                bf[j] = *reinterpret_cast<half8*>(Bt + ((jb + j) * 2 + s) * 512 + lane * 8);
#pragma unroll
            for (int i = 0; i < 4; ++i)
#pragma unroll
                for (int j = 0; j < 4; ++j)
                    acc[i][j] = MFMA16(a[i], bf[j], acc[i][j]);
        }
    }
    __syncthreads();
    f16* ct = (f16*)sm;
#pragma unroll
    for (int i = 0; i < 4; ++i)
#pragma unroll
        for (int j = 0; j < 4; ++j)
#pragma unroll
            for (int r = 0; r < 4; ++r)
                ct[(wm + i * 16 + quad * 4 + r) * 136 + wn + j * 16 + l15] = (f16)acc[i][j][r];
    __syncthreads();
#pragma unroll
    for (int it = 0; it < 8; ++it) {
        int c = it * 256 + tid, r = c >> 4, c8 = (c & 15) << 3;
        *reinterpret_cast<half8*>(comb + ((size_t)b * 2048 + mt * 128 + r) * 1024 + nb * 128 + c8) =
            *reinterpret_cast<half8*>(ct + r * 136 + c8);
    }
}

// ---------------------------------------------------------------------------
// Kernel 5: out = comb @ W_out^T (fp16 gl_lds GEMM, fp32 out). K=1024.
// 1D grid 1024, XCD swizzle (4 n-blocks of one A-strip -> same XCD).
// ---------------------------------------------------------------------------
__global__ __launch_bounds__(256) void k_out(const f16* __restrict__ comb,
                                             const f16* __restrict__ Wo16,
                                             float* __restrict__ out)
{
    __shared__ char sm[32768];
    f16* At = (f16*)sm;
    f16* Bt = (f16*)(sm + 16384);
    const int tid = threadIdx.x, lane = tid & 63, w = tid >> 6;
    const int l15 = lane & 15, quad = lane >> 4;
    const int id = blockIdx.x, xcd = id & 7, u = id >> 3;
    const int mbase = (xcd * 32 + (u >> 2)) * 128;
    const int nbase = (u & 3) * 128;
    const int wm = (w & 1) * 64, wn = (w >> 1) * 64;
    const int ia = wm >> 4, jb = wn >> 4;

    floatx4 acc[4][4];
#pragma unroll
    for (int i = 0; i < 4; ++i)
#pragma unroll
        for (int j = 0; j < 4; ++j) acc[i][j] = (floatx4)0.f;

    for (int k0 = 0; k0 < 1024; k0 += 64) {
        __syncthreads();
#pragma unroll
        for (int jr = 0; jr < 4; ++jr) {
            int bi = jr * 4 + w, i2 = bi >> 1, s = bi & 1;
            gload16(comb + (size_t)(mbase + i2 * 16 + l15) * 1024 + k0 + s * 32 + quad * 8,
                    At + bi * 512);
            gload16(Wo16 + (size_t)(nbase + i2 * 16 + l15) * 1024 + k0 + s * 32 + quad * 8,
                    Bt + bi * 512);
        }
        __syncthreads();
#pragma unroll
        for (int s = 0; s < 2; ++s) {
            half8 a[4], bf[4];
#pragma unroll
            for (int i = 0; i < 4; ++i)
                a[i] = *reinterpret_cast<half8*>(At + ((ia + i) * 2 + s) * 512 + lane * 8);
#pragma unroll
            for (int j = 0; j < 4; ++j)
                bf[j] = *reinterpret_cast<half8*>(Bt + ((jb + j) * 2 + s) * 512 + lane * 8);
#pragma unroll
            for (int i = 0; i < 4; ++i)
#pragma unroll
                for (int j = 0; j < 4; ++j)
                    acc[i][j] = MFMA16(a[i], bf[j], acc[i][j]);
        }
    }
#pragma unroll
    for (int i = 0; i < 4; ++i)
#pragma unroll
        for (int j = 0; j < 4; ++j)
#pragma unroll
            for (int r = 0; r < 4; ++r)
                out[(size_t)(mbase + wm + i * 16 + quad * 4 + r) * 512 + nbase + wn + j * 16 + l15] =
                    acc[i][j][r];
}

extern "C" void kernel_launch(void* const* d_in, const int* in_sizes, int n_in,
                              void* d_out, int out_size, void* d_ws, size_t ws_size,
                              hipStream_t stream)
{
    const float* query = (const float*)d_in[0];
    const float* W_in  = (const float*)d_in[1];
    const float* W_out = (const float*)d_in[2];
    float* out = (float*)d_out;

    // ws layout (bytes):
    //   comb fp16 [32768][1024] (mix|q)        @ 0           (67,108,864)
    //   qT   fp16 [16][512][2048]              @ 67,108,864  (33,554,432)
    //   W16  fp16 [Wi 262144 | Wo 524288]      @ 100,663,296 (1,572,864)
    //   X    @ 102,236,160:
    //     q16 fp16 [16*2048*512] (33,554,432)  -- dead after k_qin
    //     Sg fp32 [ng*136*128*128] (aliases q16; P fp16 written in-place)
    const size_t XOFF = 102236160ull;
    f16* comb = (f16*)d_ws;
    f16* qT   = comb + (size_t)32768 * 1024;
    f16* W16  = qT + (size_t)16 * 512 * 2048;
    f16* q16  = (f16*)((char*)d_ws + XOFF);
    const size_t sgb = 136ull * 16384 * 4;   // per-batch Sg bytes (fp32)
    int ng;
    if (ws_size >= XOFF + 16 * sgb)      ng = 16;
    else if (ws_size >= XOFF + 8 * sgb)  ng = 8;
    else                                 ng = 4;
    float* Sg = (float*)((char*)d_ws + XOFF);

    k_cvt<<<17152, 256, 0, stream>>>(query, W_in, W_out, q16, W16);
    k_qin<<<1024, 256, 0, stream>>>(q16, W16, comb, qT);
    for (int g = 0; g < 16 / ng; ++g) {
        k_sgemm<<<dim3(136, ng), 256, 0, stream>>>(comb, Sg, g * ng);
        k_softmax<<<dim3(512, ng), 256, 0, stream>>>(Sg);
        k_pv<<<64 * ng, 256, 0, stream>>>(Sg, qT, comb, g * ng);
    }
    k_out<<<1024, 256, 0, stream>>>(comb, W16 + 262144, out);
}